// Round 9
// baseline (125.762 us; speedup 1.0000x reference)
//
#include <hip/hip_runtime.h>
#include <math.h>

// Elementwise OxideModel 'second' branch, restructured + latency-hiding.
// R3: 49 us dispatch, VALU-bound (73% VALUBusy). R5 (algebra restructure):
// inferred ~35 us. This round: 2x float4 unroll (2 outstanding loads, 8
// independent element chains/thread) + nontemporal loads/stores.
// NOTE: __builtin_nontemporal_* requires a native clang vector type, not
// HIP's float4 class -> use ext_vector_type(4) alias for memory access.

typedef float f32x4 __attribute__((ext_vector_type(4)));

struct Scalars {
    // fallback (x<=1 series) path — mirrors reference exactly
    float E, U, K, expK, coef, fsT, IsT;
    // restructured main-path constants
    float A;   // exp(xT)          : exp(f(st)-f(sT)) = A * e
    float B;   // coef * expK      : coef*Ist = B * st*e*R(x)
    float C;   // U + coef * IsT   : inner = C - B*st*e*R(x)
};

// Q - P of A&S 5.1.56 (x^4 cancels; folded in coefficient space)
__device__ __forceinline__ float poly_N(float x) {
    return fmaf(fmaf(fmaf(0.9999936053f, x, 7.5739391756f), x, 12.4648921902f),
                x, 3.6907231885f);
}
__device__ __forceinline__ float poly_Q(float x) {
    return fmaf(fmaf(fmaf((x + 9.5733223454f), x, 25.6329561486f), x,
                     21.0996530827f), x, 3.9584969228f);
}

__device__ __forceinline__ Scalars make_scalars(float gshift, float E_param,
                                                float T_max_delta, float V_max) {
    Scalars s;
    s.E = fminf(fmaxf(expf(E_param) * 1000.0f, 1e-10f), 1e10f);
    float V = fminf(fmaxf(expf(V_max), 1e-10f), 1e10f);
    float T_max = 500.0f + 50.0f * tanhf(T_max_delta) + gshift;
    float sT = fmaxf(T_max, 1e-10f);
    s.U = sqrtf(V);
    float xT = s.E / sT;
    s.K = xT + (2.0f / 3.0f) * logf(1.5f * s.E * s.U / (sT * sT));
    s.expK = expf(s.K);
    s.fsT = s.K - xT;
    s.coef = (1.0f / 3.0f) * expf(s.fsT * 0.5f);
    float eT = expf(-xT);
    if (xT > 1.0f) {
        // restructured integral(sT): expK * sT * eT * (Q-P)/Q
        s.IsT = s.expK * sT * eT * (poly_N(xT) / poly_Q(xT));
    } else {
        // reference series branch (dead for bench params: xT = 10)
        float xs = fminf(fmaxf(xT, 1e-30f), 1.0f);
        float term = 1.0f, acc = 0.0f;
#pragma unroll 1
        for (int k = 1; k <= 25; ++k) {
            term = term * (-xs) / (float)k;
            acc += term / (float)k;
        }
        float ei = 0.5772156649015329f + logf(xs) + acc;
        s.IsT = s.expK * (sT * eT + s.E * ei);
    }
    s.A = expf(xT);
    s.B = s.coef * s.expK;
    s.C = s.U + s.coef * s.IsT;
    return s;
}

__device__ __forceinline__ float compute_one(float t, const Scalars& s) {
    float st = fmaxf(t, 1e-10f);
    float x = s.E * __builtin_amdgcn_rcpf(st);
    float e = __builtin_amdgcn_exp2f(x * -1.44269504088896f);  // exp(-x)
    if (x <= 1.0f) {
        // reference small-x path (uniformly dead for t in [300,800]: x>=6.25;
        // s_cbranch_execz skips it)
        float xs = fminf(fmaxf(x, 1e-30f), 1.0f);
        float term = 1.0f, acc = 0.0f;
#pragma unroll 1
        for (int k = 1; k <= 25; ++k) {
            term = term * (-xs) / (float)k;
            acc += term / (float)k;
        }
        float ei = 0.5772156649015329f + logf(xs) + acc;
        float e2 = expf(-x);
        float Ist = s.expK * (st * e2 + s.E * ei);
        float exp_arg = fminf(fmaxf((s.K - x) - s.fsT, -100.0f), 100.0f);
        float inner = s.U - s.coef * (Ist - s.IsT);
        float r = fmaxf(inner, 0.0f);
        return expf(exp_arg) * r * r;
    }
    // main path: out = exp(xT-x) * relu(U - coef*(Ist - IsT))^2
    //          = (A*e) * relu(C - B*st*e*(Q-P)/Q)^2
    float R = poly_N(x) * __builtin_amdgcn_rcpf(poly_Q(x));
    float inner = fmaf(-s.B * (st * e), R, s.C);
    float r = fmaxf(inner, 0.0f);
    return (s.A * e) * (r * r);
}

__device__ __forceinline__ f32x4 compute_four(f32x4 v, const Scalars& s) {
    f32x4 o;
    o.x = compute_one(v.x, s);
    o.y = compute_one(v.y, s);
    o.z = compute_one(v.z, s);
    o.w = compute_one(v.w, s);
    return o;
}

extern "C" __global__ void __launch_bounds__(256, 4)
oxide_kernel(const float* __restrict__ in,
             const float* __restrict__ p_gs,
             const float* __restrict__ p_E,
             const float* __restrict__ p_Td,
             const float* __restrict__ p_V,
             float* __restrict__ out, int n) {
    Scalars s = make_scalars(p_gs[0], p_E[0], p_Td[0], p_V[0]);

    int tid = blockIdx.x * blockDim.x + threadIdx.x;
    int stride = gridDim.x * blockDim.x;
    int n4 = n >> 2;
    const f32x4* __restrict__ in4 = (const f32x4*)in;
    f32x4* __restrict__ out4 = (f32x4*)out;

    // 2x float4 unroll: two independent loads in flight, 8 independent
    // element chains per thread per macro-iter.
    int i = tid;
    int stride2 = stride * 2;
    for (; i + stride < n4; i += stride2) {
        f32x4 va = __builtin_nontemporal_load(&in4[i]);
        f32x4 vb = __builtin_nontemporal_load(&in4[i + stride]);
        f32x4 oa = compute_four(va, s);
        f32x4 ob = compute_four(vb, s);
        __builtin_nontemporal_store(oa, &out4[i]);
        __builtin_nontemporal_store(ob, &out4[i + stride]);
    }
    if (i < n4) {
        f32x4 v = __builtin_nontemporal_load(&in4[i]);
        f32x4 o = compute_four(v, s);
        __builtin_nontemporal_store(o, &out4[i]);
    }
    // tail (n not divisible by 4) — dead for N=2^24, kept for generality
    int base = n4 << 2;
    for (int j = base + tid; j < n; j += stride) {
        out[j] = compute_one(in[j], s);
    }
}

extern "C" void kernel_launch(void* const* d_in, const int* in_sizes, int n_in,
                              void* d_out, int out_size, void* d_ws, size_t ws_size,
                              hipStream_t stream) {
    const float* in = (const float*)d_in[0];
    const float* gs = (const float*)d_in[1];
    const float* Ep = (const float*)d_in[2];
    const float* Td = (const float*)d_in[3];
    const float* Vm = (const float*)d_in[4];
    float* out = (float*)d_out;
    int n = in_sizes[0];

    const int threads = 256;
    const int blocks = 2048;  // 4 macro-iters/thread at N=2^24
    oxide_kernel<<<blocks, threads, 0, stream>>>(in, gs, Ep, Td, Vm, out, n);
}

// Round 10
// 119.033 us; speedup vs baseline: 1.0565x; 1.0565x over previous
//
#include <hip/hip_runtime.h>
#include <math.h>

// Elementwise OxideModel 'second' branch.
// Ladder: R3 faithful 49.2us (VALU-bound, 73% busy) -> R5 algebra restructure
// ~35us inferred -> R9 2x-unroll+nontemporal ~40us (NEUTRAL/worse: nt loads
// bypassed L3 where the harness's input-restore left the data resident;
// longer serial chains didn't add MLP). R10: revert nt, maximize wave-level
// parallelism: 32768 waves (4x machine capacity), exactly 2 independent
// f32x4 chains per thread, no loop.

typedef float f32x4 __attribute__((ext_vector_type(4)));

struct Scalars {
    // fallback (x<=1 series) path — mirrors reference exactly
    float E, U, K, expK, coef, fsT, IsT;
    // restructured main-path constants
    float A;   // exp(xT)          : exp(f(st)-f(sT)) = A * e
    float B;   // coef * expK      : coef*Ist = B * st*e*R(x)
    float C;   // U + coef * IsT   : inner = C - B*st*e*R(x)
};

// Q - P of A&S 5.1.56 (x^4 cancels; folded in coefficient space)
__device__ __forceinline__ float poly_N(float x) {
    return fmaf(fmaf(fmaf(0.9999936053f, x, 7.5739391756f), x, 12.4648921902f),
                x, 3.6907231885f);
}
__device__ __forceinline__ float poly_Q(float x) {
    return fmaf(fmaf(fmaf((x + 9.5733223454f), x, 25.6329561486f), x,
                     21.0996530827f), x, 3.9584969228f);
}

__device__ __forceinline__ Scalars make_scalars(float gshift, float E_param,
                                                float T_max_delta, float V_max) {
    Scalars s;
    s.E = fminf(fmaxf(expf(E_param) * 1000.0f, 1e-10f), 1e10f);
    float V = fminf(fmaxf(expf(V_max), 1e-10f), 1e10f);
    float T_max = 500.0f + 50.0f * tanhf(T_max_delta) + gshift;
    float sT = fmaxf(T_max, 1e-10f);
    s.U = sqrtf(V);
    float xT = s.E / sT;
    s.K = xT + (2.0f / 3.0f) * logf(1.5f * s.E * s.U / (sT * sT));
    s.expK = expf(s.K);
    s.fsT = s.K - xT;
    s.coef = (1.0f / 3.0f) * expf(s.fsT * 0.5f);
    float eT = expf(-xT);
    if (xT > 1.0f) {
        // restructured integral(sT): expK * sT * eT * (Q-P)/Q
        s.IsT = s.expK * sT * eT * (poly_N(xT) / poly_Q(xT));
    } else {
        // reference series branch (dead for bench params: xT = 10)
        float xs = fminf(fmaxf(xT, 1e-30f), 1.0f);
        float term = 1.0f, acc = 0.0f;
#pragma unroll 1
        for (int k = 1; k <= 25; ++k) {
            term = term * (-xs) / (float)k;
            acc += term / (float)k;
        }
        float ei = 0.5772156649015329f + logf(xs) + acc;
        s.IsT = s.expK * (sT * eT + s.E * ei);
    }
    s.A = expf(xT);
    s.B = s.coef * s.expK;
    s.C = s.U + s.coef * s.IsT;
    return s;
}

__device__ __forceinline__ float compute_one(float t, const Scalars& s) {
    float st = fmaxf(t, 1e-10f);
    float x = s.E * __builtin_amdgcn_rcpf(st);
    float e = __builtin_amdgcn_exp2f(x * -1.44269504088896f);  // exp(-x)
    if (x <= 1.0f) {
        // reference small-x path (uniformly dead for t in [300,800]: x>=6.25;
        // s_cbranch_execz skips it)
        float xs = fminf(fmaxf(x, 1e-30f), 1.0f);
        float term = 1.0f, acc = 0.0f;
#pragma unroll 1
        for (int k = 1; k <= 25; ++k) {
            term = term * (-xs) / (float)k;
            acc += term / (float)k;
        }
        float ei = 0.5772156649015329f + logf(xs) + acc;
        float e2 = expf(-x);
        float Ist = s.expK * (st * e2 + s.E * ei);
        float exp_arg = fminf(fmaxf((s.K - x) - s.fsT, -100.0f), 100.0f);
        float inner = s.U - s.coef * (Ist - s.IsT);
        float r = fmaxf(inner, 0.0f);
        return expf(exp_arg) * r * r;
    }
    // main path: out = exp(xT-x) * relu(U - coef*(Ist - IsT))^2
    //          = (A*e) * relu(C - B*st*e*(Q-P)/Q)^2
    float R = poly_N(x) * __builtin_amdgcn_rcpf(poly_Q(x));
    float inner = fmaf(-s.B * (st * e), R, s.C);
    float r = fmaxf(inner, 0.0f);
    return (s.A * e) * (r * r);
}

__device__ __forceinline__ f32x4 compute_four(f32x4 v, const Scalars& s) {
    f32x4 o;
    o.x = compute_one(v.x, s);
    o.y = compute_one(v.y, s);
    o.z = compute_one(v.z, s);
    o.w = compute_one(v.w, s);
    return o;
}

extern "C" __global__ void __launch_bounds__(256, 8)
oxide_kernel(const float* __restrict__ in,
             const float* __restrict__ p_gs,
             const float* __restrict__ p_E,
             const float* __restrict__ p_Td,
             const float* __restrict__ p_V,
             float* __restrict__ out, int n) {
    Scalars s = make_scalars(p_gs[0], p_E[0], p_Td[0], p_V[0]);

    int tid = blockIdx.x * blockDim.x + threadIdx.x;
    int nthreads = gridDim.x * blockDim.x;   // 2M
    int n4 = n >> 2;                         // 4M quads
    const f32x4* __restrict__ in4 = (const f32x4*)in;
    f32x4* __restrict__ out4 = (f32x4*)out;

    // Exactly two independent load->compute->store chains per thread
    // (no loop; plain cached loads so the restore-resident L3 copy is hit).
    int i = tid;
    int j = tid + nthreads;
    if (i < n4) {
        f32x4 va = in4[i];
        f32x4 oa = compute_four(va, s);
        out4[i] = oa;
    }
    if (j < n4) {
        f32x4 vb = in4[j];
        f32x4 ob = compute_four(vb, s);
        out4[j] = ob;
    }
    // tail (n not divisible by 4) — dead for N=2^24, kept for generality
    int base = n4 << 2;
    for (int k = base + tid; k < n; k += nthreads) {
        out[k] = compute_one(in[k], s);
    }
}

extern "C" void kernel_launch(void* const* d_in, const int* in_sizes, int n_in,
                              void* d_out, int out_size, void* d_ws, size_t ws_size,
                              hipStream_t stream) {
    const float* in = (const float*)d_in[0];
    const float* gs = (const float*)d_in[1];
    const float* Ep = (const float*)d_in[2];
    const float* Td = (const float*)d_in[3];
    const float* Vm = (const float*)d_in[4];
    float* out = (float*)d_out;
    int n = in_sizes[0];

    const int threads = 256;
    // 2 quads per thread: blocks = n4 / (2*256). For n=2^24: 8192 blocks
    // = 32768 waves = 4x machine wave capacity (fast turnover for MLP).
    int n4 = n >> 2;
    int blocks = (n4 + threads * 2 - 1) / (threads * 2);
    oxide_kernel<<<blocks, threads, 0, stream>>>(in, gs, Ep, Td, Vm, out, n);
}